// Round 1
// baseline (284.052 us; speedup 1.0000x reference)
//
#include <hip/hip_runtime.h>
#include <stdint.h>

#define T_DIM 8192
#define B_DIM 4096
#define NSEG 64                 // 64 segments x 128 rows (4 word-rows) each
#define NSTRIPE 16              // B_DIM / CTILE
#define CTILE 256               // columns per block
#define NEG_SLOPE 0.01f

// Native clang vector types: __builtin_nontemporal_* requires these.
typedef int      ivec4 __attribute__((ext_vector_type(4)));
typedef float    fvec4 __attribute__((ext_vector_type(4)));

// Round-9: single-kernel decoupled-lookback scan. Each block = 128 rows x
// 256 cols (4 waves, thread = 32 rows x 4 cols in register bit-words).
// Aggregates are published as one relaxed agent-scope u64 per column-quad
// (4 x u16, +1-encoded so 0 == not-ready; max aggregate 128+1 fits easily).
// 1024 blocks @ 4 blocks/CU = fully resident; atomic ticket renumbers
// blocks in dispatch order so polling can never deadlock regardless of
// dispatcher behavior.

__global__ __launch_bounds__(256, 4) void fused_scan(
        const int*   __restrict__ in,
        const float* __restrict__ delta,
        float*       __restrict__ out,
        unsigned long long* __restrict__ agg,   // [NSEG][B_DIM/4]
        int*         __restrict__ ticket)
{
    __shared__ int  s_tick;
    __shared__ int4 cnts[4][64];   // per-wordrow popcounts
    __shared__ int4 part[4][64];   // per-wave lookback partials

    if (threadIdx.x == 0) s_tick = atomicAdd(ticket, 1);
    __syncthreads();
    const int tick   = s_tick;
    const int stripe = tick & (NSTRIPE - 1);
    const int seg    = tick >> 4;              // 0..63, assigned in dispatch order

    const int c4      = threadIdx.x & 63;      // column-quad lane
    const int rc      = threadIdx.x >> 6;      // word-row within segment, 0..3
    const int col0    = stripe * CTILE + c4 * 4;
    const int wordrow = seg * 4 + rc;          // global word row 0..255
    const int row0    = wordrow * 32;
    const int cq      = col0 >> 2;             // column-quad index, 0..1023

    // ---- pack: stream 32 rows x 4 cols (nt loads) into 4 bit-words ----
    const ivec4* __restrict__ inv = (const ivec4*)in;
    uint32_t b0 = 0, b1 = 0, b2 = 0, b3 = 0;
#pragma unroll
    for (int r = 0; r < 32; ++r) {
        ivec4 v = __builtin_nontemporal_load(&inv[((size_t)(row0 + r) * B_DIM + col0) >> 2]);
        b0 |= ((uint32_t)v.x & 1u) << r;
        b1 |= ((uint32_t)v.y & 1u) << r;
        b2 |= ((uint32_t)v.z & 1u) << r;
        b3 |= ((uint32_t)v.w & 1u) << r;
    }
    cnts[rc][c4] = make_int4(__popc(b0), __popc(b1), __popc(b2), __popc(b3));
    __syncthreads();

    // ---- publish this segment's per-column aggregate ASAP (wave 0) ----
    if (rc == 0) {
        int4 s = cnts[0][c4];
#pragma unroll
        for (int i = 1; i < 4; ++i) {
            int4 v = cnts[i][c4];
            s.x += v.x; s.y += v.y; s.z += v.z; s.w += v.w;
        }
        unsigned long long val =
              (unsigned long long)(unsigned)(s.x + 1)
            | ((unsigned long long)(unsigned)(s.y + 1) << 16)
            | ((unsigned long long)(unsigned)(s.z + 1) << 32)
            | ((unsigned long long)(unsigned)(s.w + 1) << 48);
        __hip_atomic_store(&agg[(size_t)seg * (B_DIM / 4) + cq], val,
                           __ATOMIC_RELAXED, __HIP_MEMORY_SCOPE_AGENT);
    }

    // ---- decoupled lookback, split across waves: wave rc takes s = rc, rc+4, ...
    int c0 = 0, c1 = 0, c2 = 0, c3 = 0;
    for (int s = rc; s < seg; s += 4) {
        unsigned long long v = __hip_atomic_load(&agg[(size_t)s * (B_DIM / 4) + cq],
                                                 __ATOMIC_RELAXED, __HIP_MEMORY_SCOPE_AGENT);
        while ((v & 0xFFFFull) == 0ull) {
            __builtin_amdgcn_s_sleep(1);
            v = __hip_atomic_load(&agg[(size_t)s * (B_DIM / 4) + cq],
                                  __ATOMIC_RELAXED, __HIP_MEMORY_SCOPE_AGENT);
        }
        c0 += (int)( v        & 0xFFFF) - 1;
        c1 += (int)((v >> 16) & 0xFFFF) - 1;
        c2 += (int)((v >> 32) & 0xFFFF) - 1;
        c3 += (int)((v >> 48) & 0xFFFF) - 1;
    }
    part[rc][c4] = make_int4(c0, c1, c2, c3);
    __syncthreads();

    // ---- combine: global exclusive base + preceding word-rows in segment ----
    c0 = 0; c1 = 0; c2 = 0; c3 = 0;
#pragma unroll
    for (int i = 0; i < 4; ++i) {
        int4 v = part[i][c4];
        c0 += v.x; c1 += v.y; c2 += v.z; c3 += v.w;
    }
    for (int i = 0; i < rc; ++i) {   // rc is wave-uniform
        int4 v = cnts[i][c4];
        c0 += v.x; c1 += v.y; c2 += v.z; c3 += v.w;
    }

    const float d0 = delta[0];
    const float dd = delta[1] - d0;

    // ---- emit: leaky_relu((t+1)*d0 + ones*dd) straight from register bits ----
    fvec4* __restrict__ outv = (fvec4*)out;
#pragma unroll
    for (int r = 0; r < 32; ++r) {
        const int t = row0 + r;
        const float tp = (float)(t + 1) * d0;
        c0 += (int)((b0 >> r) & 1u);
        c1 += (int)((b1 >> r) & 1u);
        c2 += (int)((b2 >> r) & 1u);
        c3 += (int)((b3 >> r) & 1u);
        fvec4 o;
        float ox = fmaf((float)c0, dd, tp);
        float oy = fmaf((float)c1, dd, tp);
        float oz = fmaf((float)c2, dd, tp);
        float ow = fmaf((float)c3, dd, tp);
        o.x = (ox >= 0.0f) ? ox : NEG_SLOPE * ox;
        o.y = (oy >= 0.0f) ? oy : NEG_SLOPE * oy;
        o.z = (oz >= 0.0f) ? oz : NEG_SLOPE * oz;
        o.w = (ow >= 0.0f) ? ow : NEG_SLOPE * ow;
        __builtin_nontemporal_store(o, &outv[((size_t)t * B_DIM + col0) >> 2]);
    }
}

extern "C" void kernel_launch(void* const* d_in, const int* in_sizes, int n_in,
                              void* d_out, int out_size, void* d_ws, size_t ws_size,
                              hipStream_t stream) {
    const int*   in    = (const int*)d_in[0];
    const float* delta = (const float*)d_in[1];
    float*       out   = (float*)d_out;

    unsigned long long* agg = (unsigned long long*)d_ws;            // 512 KiB
    const size_t agg_bytes  = (size_t)NSEG * (B_DIM / 4) * sizeof(unsigned long long);
    int* ticket = (int*)((char*)d_ws + agg_bytes);

    // Workspace is harness-poisoned each iteration: zero the aggregate
    // array (0 == not-ready sentinel) and the ticket. Graph-capturable.
    hipMemsetAsync(d_ws, 0, agg_bytes + 64, stream);

    hipLaunchKernelGGL(fused_scan, dim3(1024), dim3(256), 0, stream,
                       in, delta, out, agg, ticket);
}